// Round 1
// 223.153 us; speedup vs baseline: 1.0292x; 1.0292x over previous
//
#include <hip/hip_runtime.h>
#include <stdint.h>

typedef unsigned short ushort_t;
typedef __attribute__((ext_vector_type(8))) short short8;
typedef __attribute__((ext_vector_type(4))) float f32x4;
typedef __attribute__((ext_vector_type(2))) uint32_t u32x2;

#define BATCH 4
#define SEQ 2048
#define DMODEL 768
#define NH 12
#define HD 64
#define QKV3 2304
#define NHEADS 48
// 0.125 (1/sqrt(64)) * log2(e): Q pre-scaled so softmax uses exp2
#define SCALE_Q 0.18033688011112042f

__device__ __forceinline__ ushort_t f2bf(float f) {
    union { float f; uint32_t u; } v; v.f = f;
    uint32_t u = v.u;
    u += 0x7FFF + ((u >> 16) & 1);   // RNE
    return (ushort_t)(u >> 16);
}

// pack two fp32 -> bf16x2 dword, RNE (HW packed convert when available)
__device__ __forceinline__ uint32_t pack_bf16(float a, float b) {
#if __has_builtin(__builtin_amdgcn_cvt_pk_bf16_f32)
    typedef __attribute__((ext_vector_type(2))) __bf16 bf16x2;
    bf16x2 r = __builtin_amdgcn_cvt_pk_bf16_f32(a, b);
    return __builtin_bit_cast(uint32_t, r);
#else
    return ((uint32_t)f2bf(b) << 16) | (uint32_t)f2bf(a);
#endif
}

// async global->LDS, 16B per lane; LDS dst = wave-uniform base + lane*16
typedef __attribute__((address_space(1))) uint32_t as1_u32;
typedef __attribute__((address_space(3))) uint32_t as3_u32;
__device__ __forceinline__ void async16(void* lds, const void* gsrc) {
    __builtin_amdgcn_global_load_lds((as1_u32*)gsrc, (as3_u32*)lds, 16, 0, 0);
}

// explicit vmcnt(0) lgkmcnt(0) drain (required before barrier w/ async LDS)
__device__ __forceinline__ void wait_vm_lgkm0() {
    __builtin_amdgcn_s_waitcnt(0x0070);
}

// cross-lane half-swaps (gfx950). Both operands read+write:
//   swap32: a.hi32lanes <-> b.lo32lanes
//   swap16: a.oddrows16 <-> b.evenrows16
__device__ __forceinline__ void swap32(uint32_t& a, uint32_t& b) {
    asm("v_permlane32_swap_b32 %0, %1" : "+v"(a), "+v"(b));
}
__device__ __forceinline__ void swap16(uint32_t& a, uint32_t& b) {
    asm("v_permlane16_swap_b32 %0, %1" : "+v"(a), "+v"(b));
}

// ---------------------------------------------------------------------------
// prep kernels
// ---------------------------------------------------------------------------
__global__ __launch_bounds__(256) void cvt_bf16(
    const float* __restrict__ in, ushort_t* __restrict__ out) {
    int i = blockIdx.x * 256 + threadIdx.x;
    float4 v = *(const float4*)(in + (size_t)i * 4);
    ushort4 o; o.x = f2bf(v.x); o.y = f2bf(v.y); o.z = f2bf(v.z); o.w = f2bf(v.w);
    *(ushort4*)(out + (size_t)i * 4) = o;
}

__global__ __launch_bounds__(256) void transpose_f32_bf16(
    const float* __restrict__ in, ushort_t* __restrict__ out, int R, int C) {
    __shared__ ushort_t t[64][72];
    const int tid = threadIdx.x;
    const int r0 = blockIdx.y * 64, c0 = blockIdx.x * 64;
#pragma unroll
    for (int i = 0; i < 4; i++) {
        int idx = tid + i * 256;
        int row = idx >> 4, c4 = (idx & 15) * 4;
        float4 v = *(const float4*)(in + (size_t)(r0 + row) * C + c0 + c4);
        ushort4 o; o.x = f2bf(v.x); o.y = f2bf(v.y); o.z = f2bf(v.z); o.w = f2bf(v.w);
        *(ushort4*)&t[row][c4] = o;
    }
    __syncthreads();
#pragma unroll
    for (int i = 0; i < 2; i++) {
        int idx = tid + i * 256;
        int oc = idx >> 3, g8 = (idx & 7) * 8;
        ushort_t tmp[8];
#pragma unroll
        for (int e = 0; e < 8; e++) tmp[e] = t[g8 + e][oc];
        *(short8*)(out + (size_t)(c0 + oc) * R + r0 + g8) = *(const short8*)tmp;
    }
}

// ---------------------------------------------------------------------------
// GEMM1: qkv = xb @ wqT^T. Q/K scattered to [which][b][h][n][d] (Q scaled);
// V written DIRECTLY transposed to vT[b*12+h][d][n] (8B token-packed stores).
// ---------------------------------------------------------------------------
__global__ __launch_bounds__(256, 2) void gemm_qkv(
    const ushort_t* __restrict__ A, const ushort_t* __restrict__ B,
    ushort_t* __restrict__ qkv, ushort_t* __restrict__ vT) {
    __shared__ ushort_t As[128 * 64];
    __shared__ ushort_t Bs[128 * 64];

    const int tid = threadIdx.x;
    const int m0 = blockIdx.y * 128, n0 = blockIdx.x * 128;
    const int lane = tid & 63, w = tid >> 6;
    const int wm = w >> 1, wn = w & 1;
    const int l16 = lane & 15, quad = lane >> 4;

    f32x4 acc[4][4];
#pragma unroll
    for (int i = 0; i < 4; i++)
#pragma unroll
        for (int j = 0; j < 4; j++) acc[i][j] = (f32x4){0.f, 0.f, 0.f, 0.f};

    int srow[4], scol[4];
#pragma unroll
    for (int j = 0; j < 4; j++) {
        int s = j * 256 + tid;
        srow[j] = s >> 3;
        scol[j] = ((s & 7) ^ (srow[j] & 7)) * 8;
    }
    const int swz0 = (quad ^ (l16 & 7)) * 8;
    const int swz1 = ((4 + quad) ^ (l16 & 7)) * 8;

    for (int kt = 0; kt < DMODEL; kt += 64) {
#pragma unroll
        for (int j = 0; j < 4; j++) {
            async16(&As[(j * 256 + w * 64) * 8],
                    A + (size_t)(m0 + srow[j]) * DMODEL + kt + scol[j]);
            async16(&Bs[(j * 256 + w * 64) * 8],
                    B + (size_t)(n0 + srow[j]) * DMODEL + kt + scol[j]);
        }
        wait_vm_lgkm0();
        __syncthreads();

        short8 a[4][2], b[4][2];
#pragma unroll
        for (int mi = 0; mi < 4; mi++) {
            int r = (wm * 64 + mi * 16 + l16) * 64;
            a[mi][0] = *(const short8*)&As[r + swz0];
            a[mi][1] = *(const short8*)&As[r + swz1];
        }
#pragma unroll
        for (int ni = 0; ni < 4; ni++) {
            int r = (wn * 64 + ni * 16 + l16) * 64;
            b[ni][0] = *(const short8*)&Bs[r + swz0];
            b[ni][1] = *(const short8*)&Bs[r + swz1];
        }
#pragma unroll
        for (int kk = 0; kk < 2; kk++)
#pragma unroll
            for (int mi = 0; mi < 4; mi++)
#pragma unroll
                for (int ni = 0; ni < 4; ni++)
                    acc[mi][ni] = __builtin_amdgcn_mfma_f32_16x16x32_bf16(
                        a[mi][kk], b[ni][kk], acc[mi][ni], 0, 0, 0);
        __syncthreads();
    }

#pragma unroll
    for (int ni = 0; ni < 4; ni++) {
        int nbase = n0 + wn * 64 + ni * 16;
        int which = nbase / DMODEL;           // block-uniform per ni
        int rem = nbase - which * DMODEL;
        int h = rem >> 6;
        int d = (rem & 63) + l16;
        if (which == 2) {
            // V^T direct: [b*12+h][d][token], 4 consecutive tokens per lane
#pragma unroll
            for (int mi = 0; mi < 4; mi++) {
                int mg = m0 + wm * 64 + mi * 16 + quad * 4;
                int b_ = mg >> 11, ns = mg & 2047;
                u32x2 pk = {pack_bf16(acc[mi][ni][0], acc[mi][ni][1]),
                            pack_bf16(acc[mi][ni][2], acc[mi][ni][3])};
                *(u32x2*)(vT + ((size_t)(b_ * NH + h) * HD + d) * SEQ + ns) = pk;
            }
        } else {
            float scale = (which == 0) ? SCALE_Q : 1.0f;
#pragma unroll
            for (int mi = 0; mi < 4; mi++) {
#pragma unroll
                for (int r = 0; r < 4; r++) {
                    int mg = m0 + wm * 64 + mi * 16 + quad * 4 + r;
                    int b_ = mg >> 11, ns = mg & 2047;
                    size_t dst = (((size_t)(which * BATCH + b_) * NH + h) * SEQ + ns) * HD + d;
                    qkv[dst] = f2bf(acc[mi][ni][r] * scale);
                }
            }
        }
    }
}

// ---------------------------------------------------------------------------
// Flash attention, S^T form, fixed-zero-max softmax.
// PV now runs at K=32: the two packed-P dword families of an ni-pair are
// redistributed across quads with permlane32_swap+permlane16_swap so each
// lane holds the 8 kv values of the 16x16x32 B-operand fragment. This
// halves PV MFMA issue (32 K16 -> 16 K32 per tile-wave) and converts
// 16 ds_read_b64 V reads into 8 ds_read_b128.
// ---------------------------------------------------------------------------
__global__ __launch_bounds__(256, 3) void attn(
    const ushort_t* __restrict__ qkv, const ushort_t* __restrict__ vT,
    ushort_t* __restrict__ ao) {
    __shared__ ushort_t smem[16384];

    const int tid = threadIdx.x;
    // XCD swizzle: all 16 Q-blocks of a head land on one XCD (bid%8 == XCD)
    const int bid = blockIdx.x;
    const int i = bid >> 3;
    const int bh = (bid & 7) + 8 * (i % 6);
    const int qt = i / 6;
    const int lane = tid & 63, w = tid >> 6;
    const int l16 = lane & 15, quad = lane >> 4;
    const int qh7 = l16 & 7;

    const ushort_t* qh = qkv + (size_t)bh * (SEQ * HD);
    const ushort_t* kh = qkv + (size_t)(NHEADS + bh) * (SEQ * HD);
    const ushort_t* vh = vT + (size_t)bh * (HD * SEQ);

    short8 aq[2][2];
#pragma unroll
    for (int mi = 0; mi < 2; mi++)
#pragma unroll
        for (int kk = 0; kk < 2; kk++) {
            int row = qt * 128 + w * 32 + mi * 16 + l16;
            aq[mi][kk] = *(const short8*)(qh + (size_t)row * HD + kk * 32 + quad * 8);
        }

    f32x4 lv[2];
    f32x4 O[4][2];
#pragma unroll
    for (int mi = 0; mi < 2; mi++) lv[mi] = (f32x4){0.f, 0.f, 0.f, 0.f};
#pragma unroll
    for (int nd = 0; nd < 4; nd++)
#pragma unroll
        for (int mi = 0; mi < 2; mi++) O[nd][mi] = (f32x4){0.f, 0.f, 0.f, 0.f};

    int srow[2], scol[2];
#pragma unroll
    for (int j = 0; j < 2; j++) {
        int s = j * 256 + tid;
        srow[j] = s >> 3;
        scol[j] = ((s & 7) ^ (srow[j] & 7)) * 8;
    }
    const int swz0 = (quad ^ qh7) * 8;
    const int swz1 = ((4 + quad) ^ qh7) * 8;

    // prologue: stage tile 0 into buffer 0
#pragma unroll
    for (int j = 0; j < 2; j++) {
        async16(&smem[(j * 256 + w * 64) * 8],
                kh + (size_t)srow[j] * HD + scol[j]);
        async16(&smem[4096 + (j * 256 + w * 64) * 8],
                vh + (size_t)srow[j] * SEQ + scol[j]);
    }

    const int NT = SEQ / 64;
    for (int t = 0; t < NT; t++) {
        wait_vm_lgkm0();
        __syncthreads();
        if (t + 1 < NT) {
            int nb = ((t + 1) & 1) * 8192, j1 = (t + 1) * 64;
#pragma unroll
            for (int j = 0; j < 2; j++) {
                async16(&smem[nb + (j * 256 + w * 64) * 8],
                        kh + (size_t)(j1 + srow[j]) * HD + scol[j]);
                async16(&smem[nb + 4096 + (j * 256 + w * 64) * 8],
                        vh + (size_t)srow[j] * SEQ + j1 + scol[j]);
            }
        }
        const ushort_t* Ks = smem + (t & 1) * 8192;
        const ushort_t* Vs = Ks + 4096;

        // per ni-pair: QK(2 sub-tiles) -> exp -> pack -> permlane-combine
        // into K=32 B fragments -> 8x mfma_16x16x32 PV
#pragma unroll
        for (int p = 0; p < 2; p++) {
            uint32_t pkv[2][2][2];   // [sub][mi][dword]
#pragma unroll
            for (int sub = 0; sub < 2; sub++) {
                const int ni = p * 2 + sub;
                int r = (ni * 16 + l16) * 64;
                short8 ak0 = *(const short8*)&Ks[r + swz0];
                short8 ak1 = *(const short8*)&Ks[r + swz1];
#pragma unroll
                for (int mi = 0; mi < 2; mi++) {
                    f32x4 s = __builtin_amdgcn_mfma_f32_16x16x32_bf16(
                        ak0, aq[mi][0], (f32x4){0.f, 0.f, 0.f, 0.f}, 0, 0, 0);
                    s = __builtin_amdgcn_mfma_f32_16x16x32_bf16(
                        ak1, aq[mi][1], s, 0, 0, 0);
                    f32x4 pr;
#pragma unroll
                    for (int rr = 0; rr < 4; rr++)
                        pr[rr] = __builtin_amdgcn_exp2f(s[rr]);
                    lv[mi] += pr;
                    pkv[sub][mi][0] = pack_bf16(pr[0], pr[1]);
                    pkv[sub][mi][1] = pack_bf16(pr[2], pr[3]);
                }
            }
            // quad redistribution: dest quad q gets kv = q*8..q*8+7 of the
            // 32-kv pair tile.  (a,b) = (even-ni, odd-ni) packed dwords:
            //  swap32(a,b): a=[a@q0,a@q1,b@q0,b@q1]  b=[a@q2,a@q3,b@q2,b@q3]
            //  swap16(a,b): a=[a@q0,a@q2',b... ] -> a=r_lo, b=r_hi fragment dwords
            short8 bp32[2];
#pragma unroll
            for (int mi = 0; mi < 2; mi++) {
                uint32_t x0 = pkv[0][mi][0], y0 = pkv[1][mi][0];
                uint32_t x1 = pkv[0][mi][1], y1 = pkv[1][mi][1];
                swap32(x0, y0); swap16(x0, y0);   // x0 = r0 (k{0,1}), y0 = r2 (k{4,5})
                swap32(x1, y1); swap16(x1, y1);   // x1 = r1 (k{2,3}), y1 = r3 (k{6,7})
                union { short8 s; uint32_t u[4]; } bu;
                bu.u[0] = x0; bu.u[1] = x1; bu.u[2] = y0; bu.u[3] = y1;
                bp32[mi] = bu.s;
            }
#pragma unroll
            for (int nd = 0; nd < 4; nd++) {
                int vrow = nd * 16 + l16;
                short8 av = *(const short8*)&Vs[vrow * 64 +
                                                (((p * 4 + quad) ^ qh7) * 8)];
#pragma unroll
                for (int mi = 0; mi < 2; mi++)
                    O[nd][mi] = __builtin_amdgcn_mfma_f32_16x16x32_bf16(
                        av, bp32[mi], O[nd][mi], 0, 0, 0);
            }
        }
    }

    // epilogue: reduce l, transpose O^T via LDS, coalesced store
    float inv[2];
#pragma unroll
    for (int mi = 0; mi < 2; mi++) {
        float l = (lv[mi][0] + lv[mi][1]) + (lv[mi][2] + lv[mi][3]);
        l += __shfl_xor(l, 16, 64);
        l += __shfl_xor(l, 32, 64);
        inv[mi] = __builtin_amdgcn_rcpf(l);
    }
    wait_vm_lgkm0();
    __syncthreads();
    ushort_t* Lt = smem;   // [128][72]
#pragma unroll
    for (int mi = 0; mi < 2; mi++)
#pragma unroll
        for (int nd = 0; nd < 4; nd++) {
            int row = w * 32 + mi * 16 + l16;
            int col = nd * 16 + quad * 4;
            uint32_t d0 = pack_bf16(O[nd][mi][0] * inv[mi], O[nd][mi][1] * inv[mi]);
            uint32_t d1 = pack_bf16(O[nd][mi][2] * inv[mi], O[nd][mi][3] * inv[mi]);
            *(u32x2*)&Lt[row * 72 + col] = (u32x2){d0, d1};
        }
    __syncthreads();

    const int b_ = bh / NH, h = bh % NH;
#pragma unroll
    for (int i2 = 0; i2 < 4; i2++) {
        int idx = tid + i2 * 256;
        int row = idx >> 3, c8 = (idx & 7) * 8;
        short8 vv = *(const short8*)&Lt[row * 72 + c8];
        *(short8*)(ao + ((size_t)(b_ * SEQ + qt * 128 + row)) * DMODEL +
                   h * HD + c8) = vv;
    }
}

// ---------------------------------------------------------------------------
// GEMM2 (unchanged)
// ---------------------------------------------------------------------------
__global__ __launch_bounds__(256, 2) void gemm_out(
    const ushort_t* __restrict__ A, const ushort_t* __restrict__ B,
    const float* __restrict__ bias, float* __restrict__ out) {
    __shared__ ushort_t As[128 * 64];
    __shared__ ushort_t Bs[128 * 64];

    const int tid = threadIdx.x;
    const int m0 = blockIdx.y * 128, n0 = blockIdx.x * 128;
    const int lane = tid & 63, w = tid >> 6;
    const int wm = w >> 1, wn = w & 1;
    const int l16 = lane & 15, quad = lane >> 4;

    f32x4 acc[4][4];
#pragma unroll
    for (int i = 0; i < 4; i++)
#pragma unroll
        for (int j = 0; j < 4; j++) acc[i][j] = (f32x4){0.f, 0.f, 0.f, 0.f};

    int srow[4], scol[4];
#pragma unroll
    for (int j = 0; j < 4; j++) {
        int s = j * 256 + tid;
        srow[j] = s >> 3;
        scol[j] = ((s & 7) ^ (srow[j] & 7)) * 8;
    }
    const int swz0 = (quad ^ (l16 & 7)) * 8;
    const int swz1 = ((4 + quad) ^ (l16 & 7)) * 8;

    for (int kt = 0; kt < DMODEL; kt += 64) {
#pragma unroll
        for (int j = 0; j < 4; j++) {
            async16(&As[(j * 256 + w * 64) * 8],
                    A + (size_t)(m0 + srow[j]) * DMODEL + kt + scol[j]);
            async16(&Bs[(j * 256 + w * 64) * 8],
                    B + (size_t)(n0 + srow[j]) * DMODEL + kt + scol[j]);
        }
        wait_vm_lgkm0();
        __syncthreads();

        short8 a[4][2], b[4][2];
#pragma unroll
        for (int mi = 0; mi < 4; mi++) {
            int r = (wm * 64 + mi * 16 + l16) * 64;
            a[mi][0] = *(const short8*)&As[r + swz0];
            a[mi][1] = *(const short8*)&As[r + swz1];
        }
#pragma unroll
        for (int ni = 0; ni < 4; ni++) {
            int r = (wn * 64 + ni * 16 + l16) * 64;
            b[ni][0] = *(const short8*)&Bs[r + swz0];
            b[ni][1] = *(const short8*)&Bs[r + swz1];
        }
#pragma unroll
        for (int kk = 0; kk < 2; kk++)
#pragma unroll
            for (int mi = 0; mi < 4; mi++)
#pragma unroll
                for (int ni = 0; ni < 4; ni++)
                    acc[mi][ni] = __builtin_amdgcn_mfma_f32_16x16x32_bf16(
                        a[mi][kk], b[ni][kk], acc[mi][ni], 0, 0, 0);
        __syncthreads();
    }

#pragma unroll
    for (int ni = 0; ni < 4; ni++) {
        int ng = n0 + wn * 64 + ni * 16 + l16;
        float bv = bias[ng];
#pragma unroll
        for (int mi = 0; mi < 4; mi++) {
#pragma unroll
            for (int r = 0; r < 4; r++) {
                int mg = m0 + wm * 64 + mi * 16 + quad * 4 + r;
                out[(size_t)mg * DMODEL + ng] = acc[mi][ni][r] + bv;
            }
        }
    }
}

extern "C" void kernel_launch(void* const* d_in, const int* in_sizes, int n_in,
                              void* d_out, int out_size, void* d_ws, size_t ws_size,
                              hipStream_t stream) {
    const float* x     = (const float*)d_in[0];
    const float* w_qkv = (const float*)d_in[1];
    const float* w_out = (const float*)d_in[2];
    const float* b_out = (const float*)d_in[3];
    float* out = (float*)d_out;

    ushort_t* xb  = (ushort_t*)d_ws;                       // 8192*768
    ushort_t* wqT = xb  + (size_t)8192 * 768;              // 2304*768
    ushort_t* woT = wqT + (size_t)QKV3 * 768;              // 768*768
    ushort_t* qkv = woT + (size_t)768 * 768;               // 3*48*2048*64 (V region unused)
    ushort_t* vT  = qkv + (size_t)3 * NHEADS * SEQ * HD;   // 48*64*2048
    ushort_t* ao  = vT  + (size_t)NHEADS * HD * SEQ;       // 8192*768

    cvt_bf16<<<dim3((8192 * 768) / 4 / 256), 256, 0, stream>>>(x, xb);
    transpose_f32_bf16<<<dim3(QKV3 / 64, DMODEL / 64), 256, 0, stream>>>(
        w_qkv, wqT, DMODEL, QKV3);
    transpose_f32_bf16<<<dim3(DMODEL / 64, DMODEL / 64), 256, 0, stream>>>(
        w_out, woT, DMODEL, DMODEL);

    gemm_qkv<<<dim3(QKV3 / 128, (BATCH * SEQ) / 128), 256, 0, stream>>>(
        xb, wqT, qkv, vT);

    attn<<<dim3(NHEADS * (SEQ / 128)), 256, 0, stream>>>(qkv, vT, ao);

    gemm_out<<<dim3(DMODEL / 128, (BATCH * SEQ) / 128), 256, 0, stream>>>(
        ao, woT, b_out, out);
}

// Round 2
// 211.140 us; speedup vs baseline: 1.0878x; 1.0569x over previous
//
#include <hip/hip_runtime.h>
#include <stdint.h>

typedef unsigned short ushort_t;
typedef __attribute__((ext_vector_type(8))) short short8;
typedef __attribute__((ext_vector_type(4))) float f32x4;
typedef __attribute__((ext_vector_type(2))) uint32_t u32x2;

#define BATCH 4
#define SEQ 2048
#define DMODEL 768
#define NH 12
#define HD 64
#define QKV3 2304
#define NHEADS 48
// 0.125 (1/sqrt(64)) * log2(e): Q pre-scaled so softmax uses exp2
#define SCALE_Q 0.18033688011112042f

__device__ __forceinline__ ushort_t f2bf(float f) {
    union { float f; uint32_t u; } v; v.f = f;
    uint32_t u = v.u;
    u += 0x7FFF + ((u >> 16) & 1);   // RNE
    return (ushort_t)(u >> 16);
}

// pack two fp32 -> bf16x2 dword, RNE (HW packed convert when available)
__device__ __forceinline__ uint32_t pack_bf16(float a, float b) {
#if __has_builtin(__builtin_amdgcn_cvt_pk_bf16_f32)
    typedef __attribute__((ext_vector_type(2))) __bf16 bf16x2;
    bf16x2 r = __builtin_amdgcn_cvt_pk_bf16_f32(a, b);
    return __builtin_bit_cast(uint32_t, r);
#else
    return ((uint32_t)f2bf(b) << 16) | (uint32_t)f2bf(a);
#endif
}

// async global->LDS, 16B per lane; LDS dst = wave-uniform base + lane*16
typedef __attribute__((address_space(1))) uint32_t as1_u32;
typedef __attribute__((address_space(3))) uint32_t as3_u32;
__device__ __forceinline__ void async16(void* lds, const void* gsrc) {
    __builtin_amdgcn_global_load_lds((as1_u32*)gsrc, (as3_u32*)lds, 16, 0, 0);
}

// explicit vmcnt(0) lgkmcnt(0) drain (required before barrier w/ async LDS)
__device__ __forceinline__ void wait_vm_lgkm0() {
    __builtin_amdgcn_s_waitcnt(0x0070);
}

// cross-lane half-swaps (gfx950). Both operands read+write:
//   swap32: a.hi32lanes <-> b.lo32lanes
//   swap16: a.oddrows16 <-> b.evenrows16
__device__ __forceinline__ void swap32(uint32_t& a, uint32_t& b) {
    asm("v_permlane32_swap_b32 %0, %1" : "+v"(a), "+v"(b));
}
__device__ __forceinline__ void swap16(uint32_t& a, uint32_t& b) {
    asm("v_permlane16_swap_b32 %0, %1" : "+v"(a), "+v"(b));
}

// ---------------------------------------------------------------------------
// prep kernels
// ---------------------------------------------------------------------------
__global__ __launch_bounds__(256) void cvt_bf16(
    const float* __restrict__ in, ushort_t* __restrict__ out) {
    int i = blockIdx.x * 256 + threadIdx.x;
    float4 v = *(const float4*)(in + (size_t)i * 4);
    ushort4 o; o.x = f2bf(v.x); o.y = f2bf(v.y); o.z = f2bf(v.z); o.w = f2bf(v.w);
    *(ushort4*)(out + (size_t)i * 4) = o;
}

__global__ __launch_bounds__(256) void transpose_f32_bf16(
    const float* __restrict__ in, ushort_t* __restrict__ out, int R, int C) {
    __shared__ ushort_t t[64][72];
    const int tid = threadIdx.x;
    const int r0 = blockIdx.y * 64, c0 = blockIdx.x * 64;
#pragma unroll
    for (int i = 0; i < 4; i++) {
        int idx = tid + i * 256;
        int row = idx >> 4, c4 = (idx & 15) * 4;
        float4 v = *(const float4*)(in + (size_t)(r0 + row) * C + c0 + c4);
        ushort4 o; o.x = f2bf(v.x); o.y = f2bf(v.y); o.z = f2bf(v.z); o.w = f2bf(v.w);
        *(ushort4*)&t[row][c4] = o;
    }
    __syncthreads();
#pragma unroll
    for (int i = 0; i < 2; i++) {
        int idx = tid + i * 256;
        int oc = idx >> 3, g8 = (idx & 7) * 8;
        ushort_t tmp[8];
#pragma unroll
        for (int e = 0; e < 8; e++) tmp[e] = t[g8 + e][oc];
        *(short8*)(out + (size_t)(c0 + oc) * R + r0 + g8) = *(const short8*)tmp;
    }
}

// ---------------------------------------------------------------------------
// GEMM1: qkv = xb @ wqT^T. Q/K scattered to [which][b][h][n][d] (Q scaled);
// V written DIRECTLY transposed to vT[b*12+h][d][n] (8B token-packed stores).
// ---------------------------------------------------------------------------
__global__ __launch_bounds__(256, 2) void gemm_qkv(
    const ushort_t* __restrict__ A, const ushort_t* __restrict__ B,
    ushort_t* __restrict__ qkv, ushort_t* __restrict__ vT) {
    __shared__ ushort_t As[128 * 64];
    __shared__ ushort_t Bs[128 * 64];

    const int tid = threadIdx.x;
    const int m0 = blockIdx.y * 128, n0 = blockIdx.x * 128;
    const int lane = tid & 63, w = tid >> 6;
    const int wm = w >> 1, wn = w & 1;
    const int l16 = lane & 15, quad = lane >> 4;

    f32x4 acc[4][4];
#pragma unroll
    for (int i = 0; i < 4; i++)
#pragma unroll
        for (int j = 0; j < 4; j++) acc[i][j] = (f32x4){0.f, 0.f, 0.f, 0.f};

    int srow[4], scol[4];
#pragma unroll
    for (int j = 0; j < 4; j++) {
        int s = j * 256 + tid;
        srow[j] = s >> 3;
        scol[j] = ((s & 7) ^ (srow[j] & 7)) * 8;
    }
    const int swz0 = (quad ^ (l16 & 7)) * 8;
    const int swz1 = ((4 + quad) ^ (l16 & 7)) * 8;

    for (int kt = 0; kt < DMODEL; kt += 64) {
#pragma unroll
        for (int j = 0; j < 4; j++) {
            async16(&As[(j * 256 + w * 64) * 8],
                    A + (size_t)(m0 + srow[j]) * DMODEL + kt + scol[j]);
            async16(&Bs[(j * 256 + w * 64) * 8],
                    B + (size_t)(n0 + srow[j]) * DMODEL + kt + scol[j]);
        }
        wait_vm_lgkm0();
        __syncthreads();

        short8 a[4][2], b[4][2];
#pragma unroll
        for (int mi = 0; mi < 4; mi++) {
            int r = (wm * 64 + mi * 16 + l16) * 64;
            a[mi][0] = *(const short8*)&As[r + swz0];
            a[mi][1] = *(const short8*)&As[r + swz1];
        }
#pragma unroll
        for (int ni = 0; ni < 4; ni++) {
            int r = (wn * 64 + ni * 16 + l16) * 64;
            b[ni][0] = *(const short8*)&Bs[r + swz0];
            b[ni][1] = *(const short8*)&Bs[r + swz1];
        }
#pragma unroll
        for (int kk = 0; kk < 2; kk++)
#pragma unroll
            for (int mi = 0; mi < 4; mi++)
#pragma unroll
                for (int ni = 0; ni < 4; ni++)
                    acc[mi][ni] = __builtin_amdgcn_mfma_f32_16x16x32_bf16(
                        a[mi][kk], b[ni][kk], acc[mi][ni], 0, 0, 0);
        __syncthreads();
    }

#pragma unroll
    for (int ni = 0; ni < 4; ni++) {
        int nbase = n0 + wn * 64 + ni * 16;
        int which = nbase / DMODEL;           // block-uniform per ni
        int rem = nbase - which * DMODEL;
        int h = rem >> 6;
        int d = (rem & 63) + l16;
        if (which == 2) {
            // V^T direct: [b*12+h][d][token], 4 consecutive tokens per lane
#pragma unroll
            for (int mi = 0; mi < 4; mi++) {
                int mg = m0 + wm * 64 + mi * 16 + quad * 4;
                int b_ = mg >> 11, ns = mg & 2047;
                u32x2 pk = {pack_bf16(acc[mi][ni][0], acc[mi][ni][1]),
                            pack_bf16(acc[mi][ni][2], acc[mi][ni][3])};
                *(u32x2*)(vT + ((size_t)(b_ * NH + h) * HD + d) * SEQ + ns) = pk;
            }
        } else {
            float scale = (which == 0) ? SCALE_Q : 1.0f;
#pragma unroll
            for (int mi = 0; mi < 4; mi++) {
#pragma unroll
                for (int r = 0; r < 4; r++) {
                    int mg = m0 + wm * 64 + mi * 16 + quad * 4 + r;
                    int b_ = mg >> 11, ns = mg & 2047;
                    size_t dst = (((size_t)(which * BATCH + b_) * NH + h) * SEQ + ns) * HD + d;
                    qkv[dst] = f2bf(acc[mi][ni][r] * scale);
                }
            }
        }
    }
}

// ---------------------------------------------------------------------------
// Flash attention, S^T form, fixed-zero-max softmax, K=32 PV via permlane
// quad-redistribution. Softmax denominator is computed on the MATRIX pipe:
// acc_l = mfma(ones_A, P_frag, acc_l) gives D[r][q] = sum_k P[k][q]
// replicated over all rows r -> every lane ends with its token's full
// denominator in acc_l[mi][0]; no VALU adds, no epilogue shuffle reduce.
// ---------------------------------------------------------------------------
__global__ __launch_bounds__(256, 3) void attn(
    const ushort_t* __restrict__ qkv, const ushort_t* __restrict__ vT,
    ushort_t* __restrict__ ao) {
    __shared__ ushort_t smem[16384];

    const int tid = threadIdx.x;
    // XCD swizzle: all 16 Q-blocks of a head land on one XCD (bid%8 == XCD)
    const int bid = blockIdx.x;
    const int i = bid >> 3;
    const int bh = (bid & 7) + 8 * (i % 6);
    const int qt = i / 6;
    const int lane = tid & 63, w = tid >> 6;
    const int l16 = lane & 15, quad = lane >> 4;
    const int qh7 = l16 & 7;

    const ushort_t* qh = qkv + (size_t)bh * (SEQ * HD);
    const ushort_t* kh = qkv + (size_t)(NHEADS + bh) * (SEQ * HD);
    const ushort_t* vh = vT + (size_t)bh * (HD * SEQ);

    short8 aq[2][2];
#pragma unroll
    for (int mi = 0; mi < 2; mi++)
#pragma unroll
        for (int kk = 0; kk < 2; kk++) {
            int row = qt * 128 + w * 32 + mi * 16 + l16;
            aq[mi][kk] = *(const short8*)(qh + (size_t)row * HD + kk * 32 + quad * 8);
        }

    // all-ones bf16 A fragment for the denominator MFMA
    short8 ones8;
#pragma unroll
    for (int j = 0; j < 8; j++) ones8[j] = (short)0x3F80;

    f32x4 acc_l[2];
    f32x4 O[4][2];
#pragma unroll
    for (int mi = 0; mi < 2; mi++) acc_l[mi] = (f32x4){0.f, 0.f, 0.f, 0.f};
#pragma unroll
    for (int nd = 0; nd < 4; nd++)
#pragma unroll
        for (int mi = 0; mi < 2; mi++) O[nd][mi] = (f32x4){0.f, 0.f, 0.f, 0.f};

    int srow[2], scol[2];
#pragma unroll
    for (int j = 0; j < 2; j++) {
        int s = j * 256 + tid;
        srow[j] = s >> 3;
        scol[j] = ((s & 7) ^ (srow[j] & 7)) * 8;
    }
    const int swz0 = (quad ^ qh7) * 8;
    const int swz1 = ((4 + quad) ^ qh7) * 8;

    // prologue: stage tile 0 into buffer 0
#pragma unroll
    for (int j = 0; j < 2; j++) {
        async16(&smem[(j * 256 + w * 64) * 8],
                kh + (size_t)srow[j] * HD + scol[j]);
        async16(&smem[4096 + (j * 256 + w * 64) * 8],
                vh + (size_t)srow[j] * SEQ + scol[j]);
    }

    const int NT = SEQ / 64;
    for (int t = 0; t < NT; t++) {
        wait_vm_lgkm0();
        __syncthreads();
        if (t + 1 < NT) {
            int nb = ((t + 1) & 1) * 8192, j1 = (t + 1) * 64;
#pragma unroll
            for (int j = 0; j < 2; j++) {
                async16(&smem[nb + (j * 256 + w * 64) * 8],
                        kh + (size_t)(j1 + srow[j]) * HD + scol[j]);
                async16(&smem[nb + 4096 + (j * 256 + w * 64) * 8],
                        vh + (size_t)srow[j] * SEQ + j1 + scol[j]);
            }
        }
        const ushort_t* Ks = smem + (t & 1) * 8192;
        const ushort_t* Vs = Ks + 4096;

        // per ni-pair: QK(2 sub-tiles) -> exp -> pack -> permlane-combine
        // into K=32 B fragments -> 8x mfma_16x16x32 PV + 2x denominator mfma
#pragma unroll
        for (int p = 0; p < 2; p++) {
            uint32_t pkv[2][2][2];   // [sub][mi][dword]
#pragma unroll
            for (int sub = 0; sub < 2; sub++) {
                const int ni = p * 2 + sub;
                int r = (ni * 16 + l16) * 64;
                short8 ak0 = *(const short8*)&Ks[r + swz0];
                short8 ak1 = *(const short8*)&Ks[r + swz1];
#pragma unroll
                for (int mi = 0; mi < 2; mi++) {
                    f32x4 s = __builtin_amdgcn_mfma_f32_16x16x32_bf16(
                        ak0, aq[mi][0], (f32x4){0.f, 0.f, 0.f, 0.f}, 0, 0, 0);
                    s = __builtin_amdgcn_mfma_f32_16x16x32_bf16(
                        ak1, aq[mi][1], s, 0, 0, 0);
                    f32x4 pr;
#pragma unroll
                    for (int rr = 0; rr < 4; rr++)
                        pr[rr] = __builtin_amdgcn_exp2f(s[rr]);
                    pkv[sub][mi][0] = pack_bf16(pr[0], pr[1]);
                    pkv[sub][mi][1] = pack_bf16(pr[2], pr[3]);
                }
            }
            // quad redistribution: dest quad q gets kv = q*8..q*8+7 of the
            // 32-kv pair tile.  (a,b) = (even-ni, odd-ni) packed dwords:
            //  swap32(a,b): a=[a@q0,a@q1,b@q0,b@q1]  b=[a@q2,a@q3,b@q2,b@q3]
            //  swap16(a,b): a=[a@q0,a@q2',b... ] -> a=r_lo, b=r_hi fragment dwords
            short8 bp32[2];
#pragma unroll
            for (int mi = 0; mi < 2; mi++) {
                uint32_t x0 = pkv[0][mi][0], y0 = pkv[1][mi][0];
                uint32_t x1 = pkv[0][mi][1], y1 = pkv[1][mi][1];
                swap32(x0, y0); swap16(x0, y0);   // x0 = r0 (k{0,1}), y0 = r2 (k{4,5})
                swap32(x1, y1); swap16(x1, y1);   // x1 = r1 (k{2,3}), y1 = r3 (k{6,7})
                union { short8 s; uint32_t u[4]; } bu;
                bu.u[0] = x0; bu.u[1] = x1; bu.u[2] = y0; bu.u[3] = y1;
                bp32[mi] = bu.s;
            }
            __builtin_amdgcn_s_setprio(1);
#pragma unroll
            for (int mi = 0; mi < 2; mi++)
                acc_l[mi] = __builtin_amdgcn_mfma_f32_16x16x32_bf16(
                    ones8, bp32[mi], acc_l[mi], 0, 0, 0);
#pragma unroll
            for (int nd = 0; nd < 4; nd++) {
                int vrow = nd * 16 + l16;
                short8 av = *(const short8*)&Vs[vrow * 64 +
                                                (((p * 4 + quad) ^ qh7) * 8)];
#pragma unroll
                for (int mi = 0; mi < 2; mi++)
                    O[nd][mi] = __builtin_amdgcn_mfma_f32_16x16x32_bf16(
                        av, bp32[mi], O[nd][mi], 0, 0, 0);
            }
            __builtin_amdgcn_s_setprio(0);
        }
    }

    // epilogue: denominator already per-lane in acc_l[mi][0];
    // transpose O^T via LDS, coalesced store
    float inv[2];
#pragma unroll
    for (int mi = 0; mi < 2; mi++)
        inv[mi] = __builtin_amdgcn_rcpf(acc_l[mi][0]);
    wait_vm_lgkm0();
    __syncthreads();
    ushort_t* Lt = smem;   // [128][72]
#pragma unroll
    for (int mi = 0; mi < 2; mi++)
#pragma unroll
        for (int nd = 0; nd < 4; nd++) {
            int row = w * 32 + mi * 16 + l16;
            int col = nd * 16 + quad * 4;
            uint32_t d0 = pack_bf16(O[nd][mi][0] * inv[mi], O[nd][mi][1] * inv[mi]);
            uint32_t d1 = pack_bf16(O[nd][mi][2] * inv[mi], O[nd][mi][3] * inv[mi]);
            *(u32x2*)&Lt[row * 72 + col] = (u32x2){d0, d1};
        }
    __syncthreads();

    const int b_ = bh / NH, h = bh % NH;
#pragma unroll
    for (int i2 = 0; i2 < 4; i2++) {
        int idx = tid + i2 * 256;
        int row = idx >> 3, c8 = (idx & 7) * 8;
        short8 vv = *(const short8*)&Lt[row * 72 + c8];
        *(short8*)(ao + ((size_t)(b_ * SEQ + qt * 128 + row)) * DMODEL +
                   h * HD + c8) = vv;
    }
}

// ---------------------------------------------------------------------------
// GEMM2 (unchanged)
// ---------------------------------------------------------------------------
__global__ __launch_bounds__(256, 2) void gemm_out(
    const ushort_t* __restrict__ A, const ushort_t* __restrict__ B,
    const float* __restrict__ bias, float* __restrict__ out) {
    __shared__ ushort_t As[128 * 64];
    __shared__ ushort_t Bs[128 * 64];

    const int tid = threadIdx.x;
    const int m0 = blockIdx.y * 128, n0 = blockIdx.x * 128;
    const int lane = tid & 63, w = tid >> 6;
    const int wm = w >> 1, wn = w & 1;
    const int l16 = lane & 15, quad = lane >> 4;

    f32x4 acc[4][4];
#pragma unroll
    for (int i = 0; i < 4; i++)
#pragma unroll
        for (int j = 0; j < 4; j++) acc[i][j] = (f32x4){0.f, 0.f, 0.f, 0.f};

    int srow[4], scol[4];
#pragma unroll
    for (int j = 0; j < 4; j++) {
        int s = j * 256 + tid;
        srow[j] = s >> 3;
        scol[j] = ((s & 7) ^ (srow[j] & 7)) * 8;
    }
    const int swz0 = (quad ^ (l16 & 7)) * 8;
    const int swz1 = ((4 + quad) ^ (l16 & 7)) * 8;

    for (int kt = 0; kt < DMODEL; kt += 64) {
#pragma unroll
        for (int j = 0; j < 4; j++) {
            async16(&As[(j * 256 + w * 64) * 8],
                    A + (size_t)(m0 + srow[j]) * DMODEL + kt + scol[j]);
            async16(&Bs[(j * 256 + w * 64) * 8],
                    B + (size_t)(n0 + srow[j]) * DMODEL + kt + scol[j]);
        }
        wait_vm_lgkm0();
        __syncthreads();

        short8 a[4][2], b[4][2];
#pragma unroll
        for (int mi = 0; mi < 4; mi++) {
            int r = (wm * 64 + mi * 16 + l16) * 64;
            a[mi][0] = *(const short8*)&As[r + swz0];
            a[mi][1] = *(const short8*)&As[r + swz1];
        }
#pragma unroll
        for (int ni = 0; ni < 4; ni++) {
            int r = (wn * 64 + ni * 16 + l16) * 64;
            b[ni][0] = *(const short8*)&Bs[r + swz0];
            b[ni][1] = *(const short8*)&Bs[r + swz1];
        }
#pragma unroll
        for (int kk = 0; kk < 2; kk++)
#pragma unroll
            for (int mi = 0; mi < 4; mi++)
#pragma unroll
                for (int ni = 0; ni < 4; ni++)
                    acc[mi][ni] = __builtin_amdgcn_mfma_f32_16x16x32_bf16(
                        a[mi][kk], b[ni][kk], acc[mi][ni], 0, 0, 0);
        __syncthreads();
    }

#pragma unroll
    for (int ni = 0; ni < 4; ni++) {
        int ng = n0 + wn * 64 + ni * 16 + l16;
        float bv = bias[ng];
#pragma unroll
        for (int mi = 0; mi < 4; mi++) {
#pragma unroll
            for (int r = 0; r < 4; r++) {
                int mg = m0 + wm * 64 + mi * 16 + quad * 4 + r;
                out[(size_t)mg * DMODEL + ng] = acc[mi][ni][r] + bv;
            }
        }
    }
}

extern "C" void kernel_launch(void* const* d_in, const int* in_sizes, int n_in,
                              void* d_out, int out_size, void* d_ws, size_t ws_size,
                              hipStream_t stream) {
    const float* x     = (const float*)d_in[0];
    const float* w_qkv = (const float*)d_in[1];
    const float* w_out = (const float*)d_in[2];
    const float* b_out = (const float*)d_in[3];
    float* out = (float*)d_out;

    ushort_t* xb  = (ushort_t*)d_ws;                       // 8192*768
    ushort_t* wqT = xb  + (size_t)8192 * 768;              // 2304*768
    ushort_t* woT = wqT + (size_t)QKV3 * 768;              // 768*768
    ushort_t* qkv = woT + (size_t)768 * 768;               // 3*48*2048*64 (V region unused)
    ushort_t* vT  = qkv + (size_t)3 * NHEADS * SEQ * HD;   // 48*64*2048
    ushort_t* ao  = vT  + (size_t)NHEADS * HD * SEQ;       // 8192*768

    cvt_bf16<<<dim3((8192 * 768) / 4 / 256), 256, 0, stream>>>(x, xb);
    transpose_f32_bf16<<<dim3(QKV3 / 64, DMODEL / 64), 256, 0, stream>>>(
        w_qkv, wqT, DMODEL, QKV3);
    transpose_f32_bf16<<<dim3(DMODEL / 64, DMODEL / 64), 256, 0, stream>>>(
        w_out, woT, DMODEL, DMODEL);

    gemm_qkv<<<dim3(QKV3 / 128, (BATCH * SEQ) / 128), 256, 0, stream>>>(
        xb, wqT, qkv, vT);

    attn<<<dim3(NHEADS * (SEQ / 128)), 256, 0, stream>>>(qkv, vT, ao);

    gemm_out<<<dim3(DMODEL / 128, (BATCH * SEQ) / 128), 256, 0, stream>>>(
        ao, woT, b_out, out);
}